// Round 5
// baseline (2121.633 us; speedup 1.0000x reference)
//
#include <hip/hip_runtime.h>
#include <math.h>

// ---- problem constants ----
#define BB 8
#define NN 2048
#define PSZ 32
#define PP 64
#define DD 1024
#define MLPD 2048
#define DEPTH_ 6
#define HH 8
#define DHH 64
#define INNER_ 512
#define KK 20
#define TOK 65
#define EPSF 1e-5f

#define GEMM_ACC 1
#define GEMM_GELU 2
#define GEMM_OUTBF16 4

typedef __bf16 bf16_t;
typedef __attribute__((ext_vector_type(8))) __bf16 bf16x8;
typedef __attribute__((ext_vector_type(4))) float f32x4;

// async global->LDS 16B: HW writes lds_base(wave-uniform) + lane*16
__device__ __forceinline__ void async_copy16(const bf16_t* gsrc, bf16_t* ldst) {
    __builtin_amdgcn_global_load_lds(
        (const __attribute__((address_space(1))) unsigned int*)gsrc,
        (__attribute__((address_space(3))) unsigned int*)ldst,
        16, 0, 0);
}

// x [B,N,3] -> pts [B,3,N]
__global__ void transpose_x_kernel(const float* __restrict__ x, float* __restrict__ pts) {
    int gid = blockIdx.x * blockDim.x + threadIdx.x;
    if (gid >= BB * NN * 3) return;
    int c = gid % 3; int n = (gid / 3) % NN; int b = gid / (3 * NN);
    pts[(b * 3 + c) * NN + n] = x[gid];
}

// xx[b,n] = sum_c x[b,c,n]^2
__global__ void sqnorm_kernel(const float* __restrict__ x, int bs, int C, float* __restrict__ xx) {
    int gid = blockIdx.x * blockDim.x + threadIdx.x;
    if (gid >= BB * NN) return;
    int n = gid % NN; int b = gid / NN;
    const float* xp = x + b * bs + n;
    float s = 0.f;
    for (int c = 0; c < C; ++c) { float v = xp[c * NN]; s += v * v; }
    xx[gid] = s;
}

// dist[n,m] = 2*sum_c x[c,n]x[c,m] - xx[n] - xx[m]  (symmetric)
// Upper-triangle tile grid: 136 of 256 128x128 tiles per batch; off-diagonal
// tiles mirror via LDS transpose (write volume unchanged, compute 0.53x).
__global__ __launch_bounds__(256) void dist_kernel(const float* __restrict__ x, int bs, int C,
                                                   const float* __restrict__ xx, int b0,
                                                   float* __restrict__ dist) {
    __shared__ __align__(16) float smem[4224];   // As[16][132] + Bs[16][132]  ==  tb[32][132]
    float (*As)[132] = (float(*)[132])smem;
    float (*Bs)[132] = (float(*)[132])(smem + 16 * 132);
    float (*tb)[132] = (float(*)[132])smem;

    // triangular decode: blockIdx.x in [0,136) -> (bi,bj), bi <= bj
    int q = blockIdx.x;
    int bi = 0, rem = q;
    while (rem >= (16 - bi)) { rem -= (16 - bi); ++bi; }
    int bj = bi + rem;

    int b = b0 + blockIdx.z;
    int n0 = bi * 128, m0 = bj * 128;
    int tid = threadIdx.x;
    int ty = tid >> 4, tx = tid & 15;
    float acc[2][2][4][4] = {};
    const float* xb = x + (long)b * bs;
    for (int k0 = 0; k0 < C; k0 += 16) {
        #pragma unroll
        for (int p = 0; p < 2; ++p) {
            int li = tid + p * 256;        // 0..511 float4-chunks
            int i4 = li & 31;              // float4 index within 128-wide row
            int kk = li >> 5;              // 0..15
            int c = k0 + kk;
            float4 va = make_float4(0.f, 0.f, 0.f, 0.f);
            float4 vb = va;
            if (c < C) {
                va = *(const float4*)&xb[(long)c * NN + n0 + i4 * 4];
                vb = *(const float4*)&xb[(long)c * NN + m0 + i4 * 4];
            }
            *(float4*)&As[kk][i4 * 4] = va;
            *(float4*)&Bs[kk][i4 * 4] = vb;
        }
        __syncthreads();
        #pragma unroll
        for (int kk = 0; kk < 16; ++kk) {
            float a[2][4], bv[2][4];
            *(float4*)a[0] = *(const float4*)&As[kk][ty * 4];
            *(float4*)a[1] = *(const float4*)&As[kk][64 + ty * 4];
            *(float4*)bv[0] = *(const float4*)&Bs[kk][tx * 4];
            *(float4*)bv[1] = *(const float4*)&Bs[kk][64 + tx * 4];
            #pragma unroll
            for (int ri = 0; ri < 2; ++ri)
                #pragma unroll
                for (int ci = 0; ci < 2; ++ci)
                    #pragma unroll
                    for (int i = 0; i < 4; ++i)
                        #pragma unroll
                        for (int j = 0; j < 4; ++j)
                            acc[ri][ci][i][j] += a[ri][i] * bv[ci][j];
        }
        __syncthreads();
    }
    float* db = dist + (long)blockIdx.z * NN * NN;
    const float* xxb = xx + b * NN;
    float xm[2][4];
    #pragma unroll
    for (int ci = 0; ci < 2; ++ci)
        #pragma unroll
        for (int j = 0; j < 4; ++j)
            xm[ci][j] = xxb[m0 + ci * 64 + tx * 4 + j];
    #pragma unroll
    for (int ri = 0; ri < 2; ++ri)
        #pragma unroll
        for (int i = 0; i < 4; ++i) {
            float xn = xxb[n0 + ri * 64 + ty * 4 + i];
            #pragma unroll
            for (int ci = 0; ci < 2; ++ci)
                #pragma unroll
                for (int j = 0; j < 4; ++j)
                    acc[ri][ci][i][j] = 2.f * acc[ri][ci][i][j] - xn - xm[ci][j];
        }
    // direct tile write
    #pragma unroll
    for (int ri = 0; ri < 2; ++ri)
        #pragma unroll
        for (int i = 0; i < 4; ++i) {
            int n = n0 + ri * 64 + ty * 4 + i;
            #pragma unroll
            for (int ci = 0; ci < 2; ++ci)
                *(float4*)&db[(long)n * NN + m0 + ci * 64 + tx * 4] = *(float4*)&acc[ri][ci][i][0];
        }
    // mirror tile write via LDS transpose, 4 slabs of 32 rows
    if (bi != bj) {
        #pragma unroll
        for (int s = 0; s < 4; ++s) {
            __syncthreads();
            int ci = s >> 1;
            if ((tx >> 3) == (s & 1)) {
                #pragma unroll
                for (int ri = 0; ri < 2; ++ri)
                    #pragma unroll
                    for (int j = 0; j < 4; ++j) {
                        float4 v;
                        v.x = acc[ri][ci][0][j];
                        v.y = acc[ri][ci][1][j];
                        v.z = acc[ri][ci][2][j];
                        v.w = acc[ri][ci][3][j];
                        *(float4*)&tb[(tx & 7) * 4 + j][ri * 64 + ty * 4] = v;
                    }
            }
            __syncthreads();
            int r = tid >> 3;              // 0..31
            int c0 = (tid & 7) * 16;       // 0..112
            long orow = (long)(m0 + s * 32 + r) * NN + n0 + c0;
            #pragma unroll
            for (int c4 = 0; c4 < 4; ++c4)
                *(float4*)&db[orow + c4 * 4] = *(const float4*)&tb[r][c0 + c4 * 4];
        }
    }
}

// one WAVE per row of 2048. Exact top-20 via threshold + compact + bitonic.
__global__ __launch_bounds__(256) void topk_kernel(const float* __restrict__ dist, int b0,
                                                   int* __restrict__ idx) {
    __shared__ float cval[4][64];
    __shared__ int   cidx[4][64];
    int b = b0 + blockIdx.y;
    int wid = threadIdx.x >> 6, lane = threadIdx.x & 63;
    int n = blockIdx.x * 4 + wid;
    const float* row = dist + ((long)blockIdx.y * NN + n) * NN;
    float vals[32];
    #pragma unroll
    for (int s = 0; s < 32; ++s) vals[s] = row[s * 64 + lane];
    int* op = idx + ((long)b * NN + n) * KK;

    float lm = vals[0];
    #pragma unroll
    for (int s = 1; s < 32; ++s) lm = fmaxf(lm, vals[s]);

    float sv = lm;
    #pragma unroll
    for (int k = 2; k <= 64; k <<= 1) {
        #pragma unroll
        for (int j = k >> 1; j > 0; j >>= 1) {
            float pv = __shfl_xor(sv, j);
            bool lower = (lane & j) == 0;
            bool up = (lane & k) != 0;
            bool ownBetter = sv > pv;
            bool keepOwn = ownBetter ^ (lower == up);
            sv = keepOwn ? sv : pv;
        }
    }
    float t = __shfl(sv, 19);   // 20th largest lane-max

    int base = 0;
    #pragma unroll
    for (int s = 0; s < 32; ++s) {
        bool q = vals[s] >= t;
        unsigned long long m = __ballot(q);
        int my = base + (int)__builtin_amdgcn_mbcnt_hi((unsigned)(m >> 32),
                         __builtin_amdgcn_mbcnt_lo((unsigned)m, 0u));
        if (q && my < 64) { cval[wid][my] = vals[s]; cidx[wid][my] = s * 64 + lane; }
        base += (int)__popcll(m);
    }
    __asm__ volatile("s_waitcnt lgkmcnt(0)" ::: "memory");

    if (base <= 64) {
        float v = (lane < base) ? cval[wid][lane] : -INFINITY;
        int   ii = (lane < base) ? cidx[wid][lane] : 0x7FFFFFFF;
        #pragma unroll
        for (int k = 2; k <= 64; k <<= 1) {
            #pragma unroll
            for (int j = k >> 1; j > 0; j >>= 1) {
                float pv = __shfl_xor(v, j);
                int   pi = __shfl_xor(ii, j);
                bool lower = (lane & j) == 0;
                bool up = (lane & k) != 0;
                bool ownBetter = (v > pv) || (v == pv && ii < pi);
                bool keepOwn = ownBetter ^ (lower == up);
                if (!keepOwn) { v = pv; ii = pi; }
            }
        }
        if (lane < KK) op[lane] = ii;
    } else {
        for (int kk = 0; kk < KK; ++kk) {
            float bv = vals[0]; int bsl = 0;
            #pragma unroll
            for (int s = 1; s < 32; ++s) if (vals[s] > bv) { bv = vals[s]; bsl = s; }
            int bm = bsl * 64 + lane;
            for (int off = 32; off; off >>= 1) {
                float ov = __shfl_xor(bv, off);
                int om = __shfl_xor(bm, off);
                if (ov > bv || (ov == bv && om < bm)) { bv = ov; bm = om; }
            }
            int wslot = bm >> 6, wlane = bm & 63;
            #pragma unroll
            for (int s = 0; s < 32; ++s)
                if (s == wslot) vals[s] = (lane == wlane) ? -INFINITY : vals[s];
            if (lane == 0) op[kk] = bm;
        }
    }
}

// p/q (fp32, LDS tiled)
__global__ __launch_bounds__(256) void pq_kernel(const float* __restrict__ x, int bs, int C,
                                                 const float* __restrict__ w, int O,
                                                 float* __restrict__ p, float* __restrict__ q) {
    __shared__ float wT[256][33];
    __shared__ float xs[128][32];
    int b = blockIdx.z;
    int o0 = blockIdx.y * 32;
    int n0 = blockIdx.x * 32;
    int tid = threadIdx.x;
    for (int i = tid; i < 2 * C * 32; i += 256) {
        int c2 = i % (2 * C), o = i / (2 * C);
        wT[c2][o] = w[(o0 + o) * 2 * C + c2];
    }
    for (int i = tid; i < C * 32; i += 256) {
        int nl = i % 32, c = i / 32;
        xs[c][nl] = x[b * bs + c * NN + n0 + nl];
    }
    __syncthreads();
    int o_l = tid & 31;
    int n_base = (tid >> 5) * 4;
    float ps[4] = {0.f, 0.f, 0.f, 0.f};
    float qs[4] = {0.f, 0.f, 0.f, 0.f};
    for (int c = 0; c < C; ++c) {
        float4 xv = *(const float4*)&xs[c][n_base];
        float wa = wT[c][o_l];
        float wb = wT[C + c][o_l];
        float d = wb - wa;
        ps[0] += xv.x * wa; qs[0] += xv.x * d;
        ps[1] += xv.y * wa; qs[1] += xv.y * d;
        ps[2] += xv.z * wa; qs[2] += xv.z * d;
        ps[3] += xv.w * wa; qs[3] += xv.w * d;
    }
    for (int j = 0; j < 4; ++j) {
        long r = (long)(b * NN + n0 + n_base + j) * O + o0 + o_l;
        p[r] = ps[j];
        q[r] = qs[j];
    }
}

__global__ void zero_stats_kernel(double* __restrict__ s1, double* __restrict__ s2) {
    int t = blockIdx.x * blockDim.x + threadIdx.x;
    if (t < 1024) { s1[t] = 0.0; s2[t] = 0.0; }
}

// FUSED gather: one pass computes BN stats (sum, sumsq via per-block atomics)
// AND per-(row,o) max/min of v = p[j]+q[r] (coalesced writes into maxb/minb).
__global__ __launch_bounds__(256) void edge_gather_kernel(const float* __restrict__ p,
                                                          const float* __restrict__ q,
                                                          const int* __restrict__ idx, int O,
                                                          double* __restrict__ gsum,
                                                          double* __restrict__ gsumsq,
                                                          float* __restrict__ maxb,
                                                          float* __restrict__ minb) {
    int tid = threadIdx.x;
    int o = tid % O;
    int grp = tid / O;
    int ngrp = 256 / O;
    int rows_per_blk = (BB * NN) / gridDim.x;
    int r0 = blockIdx.x * rows_per_blk;
    double s = 0.0, ss = 0.0;
    for (int r = r0 + grp; r < r0 + rows_per_blk; r += ngrp) {
        int b = r / NN;
        float qv = q[(long)r * O + o];
        const int* ip = idx + (long)r * KK;
        float mx = -INFINITY, mn = INFINITY;
        for (int k = 0; k < KK; ++k) {
            int j = ip[k];
            float v = p[(long)(b * NN + j) * O + o] + qv;
            s += v; ss += (double)v * v;
            mx = fmaxf(mx, v); mn = fminf(mn, v);
        }
        maxb[(long)r * O + o] = mx;
        minb[(long)r * O + o] = mn;
    }
    atomicAdd(&gsum[o], s);
    atomicAdd(&gsumsq[o], ss);
}

__global__ void bn_finalize_kernel(const double* __restrict__ gsum, const double* __restrict__ gsumsq,
                                   const float* __restrict__ g, const float* __restrict__ bb, int O, double cnt,
                                   float* __restrict__ scale, float* __restrict__ shift) {
    int o = blockIdx.x * blockDim.x + threadIdx.x;
    if (o >= O) return;
    double mean = gsum[o] / cnt;
    double var = gsumsq[o] / cnt - mean * mean;
    float inv = rsqrtf((float)var + EPSF);
    float sc = g[o] * inv;
    scale[o] = sc;
    shift[o] = bb[o] - (float)mean * sc;
}

// elementwise finalize: out[b][o][n] = lrelu(sc*(sc>=0?max:min)+sh), LDS-transposed
// (monotone lrelu => max over k commutes with the affine BN map; sign picks max/min)
__global__ __launch_bounds__(256) void edge_finalize_kernel(const float* __restrict__ maxb,
                                                            const float* __restrict__ minb, int O,
                                                            const float* __restrict__ scale,
                                                            const float* __restrict__ shift,
                                                            float* __restrict__ out, int obs) {
    __shared__ float tile[32][33];
    int b = blockIdx.z;
    int o0 = blockIdx.y * 32, n0 = blockIdx.x * 32;
    int tx = threadIdx.x & 31, tg = threadIdx.x >> 5;
    float sc = scale[o0 + tx], sh = shift[o0 + tx];
    for (int i = 0; i < 4; ++i) {
        int n = tg + i * 8;
        long rr = (long)(b * NN + n0 + n) * O + o0 + tx;
        float base = (sc >= 0.f) ? maxb[rr] : minb[rr];
        float a = sc * base + sh;
        tile[n][tx] = (a >= 0.f) ? a : 0.2f * a;
    }
    __syncthreads();
    for (int i = 0; i < 4; ++i) {
        int o = tg + i * 8;
        out[(long)b * obs + (long)(o0 + o) * NN + n0 + tx] = tile[tx][o];
    }
}

// legacy two-pass path (tight-workspace mode only)
__global__ __launch_bounds__(256) void edge_stats_kernel(const float* __restrict__ p, const float* __restrict__ q,
                                                         const int* __restrict__ idx, int O,
                                                         double* __restrict__ gsum, double* __restrict__ gsumsq) {
    int tid = threadIdx.x;
    int o = tid % O;
    int grp = tid / O;
    int ngrp = 256 / O;
    int rows_per_blk = (BB * NN) / gridDim.x;
    int r0 = blockIdx.x * rows_per_blk;
    double s = 0.0, ss = 0.0;
    for (int r = r0 + grp; r < r0 + rows_per_blk; r += ngrp) {
        int b = r / NN;
        float qv = q[r * O + o];
        for (int k = 0; k < KK; ++k) {
            int j = idx[r * KK + k];
            float v = p[(b * NN + j) * O + o] + qv;
            s += v; ss += (double)v * v;
        }
    }
    atomicAdd(&gsum[o], s);
    atomicAdd(&gsumsq[o], ss);
}

__global__ void edge_out_kernel(const float* __restrict__ p, const float* __restrict__ q,
                                const int* __restrict__ idx, int O,
                                const float* __restrict__ scale, const float* __restrict__ shift,
                                float* __restrict__ out, int obs) {
    int gid = blockIdx.x * blockDim.x + threadIdx.x;
    if (gid >= BB * NN * O) return;
    int o = gid % O; int n = (gid / O) % NN; int b = gid / (O * NN);
    int r = b * NN + n;
    float qv = q[r * O + o];
    float sc = scale[o], sh = shift[o];
    float m = -INFINITY;
    for (int k = 0; k < KK; ++k) {
        int j = idx[r * KK + k];
        float v = (p[(b * NN + j) * O + o] + qv) * sc + sh;
        v = (v >= 0.f) ? v : 0.2f * v;
        m = fmaxf(m, v);
    }
    out[b * obs + o * NN + n] = m;
}

// transpose + fp32->bf16: in [R][C] -> out [C][R] bf16, batched in z
__global__ __launch_bounds__(256) void transpose_cvt_kernel(const float* __restrict__ in,
                                                            bf16_t* __restrict__ outp,
                                                            int R, int C, long s_in, long s_out) {
    __shared__ float tile[32][33];
    const float* ib = in + (long)blockIdx.z * s_in;
    bf16_t* ob = outp + (long)blockIdx.z * s_out;
    int r0 = blockIdx.y * 32, c0 = blockIdx.x * 32;
    int tx = threadIdx.x & 31, tg = threadIdx.x >> 5;
    for (int i = 0; i < 4; ++i) {
        int r = tg + i * 8;
        tile[r][tx] = ib[(long)(r0 + r) * C + c0 + tx];
    }
    __syncthreads();
    for (int i = 0; i < 4; ++i) {
        int c = tg + i * 8;
        ob[(long)(c0 + c) * R + r0 + tx] = (bf16_t)tile[tx][c];
    }
}

// elementwise fp32 -> bf16 (8 per thread)
__global__ void cvt_bf16_kernel(const float* __restrict__ in, bf16_t* __restrict__ outp, long n8) {
    long g = (long)blockIdx.x * blockDim.x + threadIdx.x;
    if (g >= n8) return;
    const float4* pp = (const float4*)(in + g * 8);
    float4 a = pp[0], b = pp[1];
    bf16x8 v;
    v[0] = (bf16_t)a.x; v[1] = (bf16_t)a.y; v[2] = (bf16_t)a.z; v[3] = (bf16_t)a.w;
    v[4] = (bf16_t)b.x; v[5] = (bf16_t)b.y; v[6] = (bf16_t)b.z; v[7] = (bf16_t)b.w;
    *(bf16x8*)(outp + g * 8) = v;
}

// bf16 MFMA GEMM: out[M,N] = A[M,K] x Bt[N,K]^T   (A and Bt both bf16)
// 64x64 tile, BK=32, 4 waves each computing a 32x32 quadrant via 2x2 mfma_16x16x32.
// Both operands staged via global_load_lds width-16.
__global__ __launch_bounds__(256) void gemm_bf16_kernel(const bf16_t* __restrict__ A,
                                                        const bf16_t* __restrict__ Bt,
                                                        const float* __restrict__ bias,
                                                        float* __restrict__ out,
                                                        int M, int Kd, int Nd,
                                                        long sA, long sBt, long sO, int flags) {
    __shared__ __align__(16) bf16_t As[64 * 32];
    __shared__ __align__(16) bf16_t Bs[64 * 32];
    const bf16_t* Ab = A + (long)blockIdx.z * sA;
    const bf16_t* Bb = Bt + (long)blockIdx.z * sBt;
    int row0 = blockIdx.y * 64, col0 = blockIdx.x * 64;
    int tid = threadIdx.x;
    int lane = tid & 63, wv = tid >> 6;
    int wm = wv >> 1, wn = wv & 1;
    int srow = tid & 63;
    int sk = wv * 8;
    const bf16_t* ap = Ab + (long)(row0 + srow) * Kd + sk;
    const bf16_t* bp = Bb + (long)(col0 + srow) * Kd + sk;
    bf16_t* lA = &As[wv * 512];
    bf16_t* lB = &Bs[wv * 512];
    f32x4 acc[2][2] = {};
    for (int k0 = 0; k0 < Kd; k0 += 32) {
        async_copy16(ap + k0, lA);
        async_copy16(bp + k0, lB);
        __syncthreads();
        int q = lane >> 4, cl = lane & 15;
        bf16x8 a0v = *(const bf16x8*)&As[(q * 64 + wm * 32 + cl) * 8];
        bf16x8 a1v = *(const bf16x8*)&As[(q * 64 + wm * 32 + 16 + cl) * 8];
        bf16x8 b0v = *(const bf16x8*)&Bs[(q * 64 + wn * 32 + cl) * 8];
        bf16x8 b1v = *(const bf16x8*)&Bs[(q * 64 + wn * 32 + 16 + cl) * 8];
        acc[0][0] = __builtin_amdgcn_mfma_f32_16x16x32_bf16(a0v, b0v, acc[0][0], 0, 0, 0);
        acc[0][1] = __builtin_amdgcn_mfma_f32_16x16x32_bf16(a0v, b1v, acc[0][1], 0, 0, 0);
        acc[1][0] = __builtin_amdgcn_mfma_f32_16x16x32_bf16(a1v, b0v, acc[1][0], 0, 0, 0);
        acc[1][1] = __builtin_amdgcn_mfma_f32_16x16x32_bf16(a1v, b1v, acc[1][1], 0, 0, 0);
        __syncthreads();
    }
    int q = lane >> 4, cl = lane & 15;
    float* Obf = out + (long)blockIdx.z * sO;
    bf16_t* Obh = (bf16_t*)out + (long)blockIdx.z * sO;
    for (int mt = 0; mt < 2; ++mt)
        for (int nt = 0; nt < 2; ++nt)
            #pragma unroll
            for (int r = 0; r < 4; ++r) {
                int row = row0 + wm * 32 + mt * 16 + q * 4 + r;
                if (row >= M) continue;
                int col = col0 + wn * 32 + nt * 16 + cl;
                float v = acc[mt][nt][r];
                if (bias) v += bias[col];
                if (flags & GEMM_GELU) v = 0.5f * v * (1.f + erff(v * 0.70710678118654752f));
                long oidx = (long)row * Nd + col;
                if (flags & GEMM_OUTBF16) Obh[oidx] = (bf16_t)v;
                else if (flags & GEMM_ACC) Obf[oidx] += v;
                else Obf[oidx] = v;
            }
}

// BN5 stats over bf16 y5 [b,d,n]
__global__ __launch_bounds__(256) void bn5_stats_bf16_kernel(const bf16_t* __restrict__ y5,
                                                             const float* __restrict__ g,
                                                             const float* __restrict__ bb,
                                                             float* __restrict__ scale, float* __restrict__ shift) {
    __shared__ double ssum[256], ssq[256];
    int d = blockIdx.x;
    int tid = threadIdx.x;
    double s = 0.0, sq = 0.0;
    for (int b = 0; b < BB; ++b) {
        const bf16_t* row = y5 + ((long)b * DD + d) * NN;
        for (int n = tid; n < NN; n += 256) { float v = (float)row[n]; s += v; sq += (double)v * v; }
    }
    ssum[tid] = s; ssq[tid] = sq;
    __syncthreads();
    for (int st = 128; st > 0; st >>= 1) {
        if (tid < st) { ssum[tid] += ssum[tid + st]; ssq[tid] += ssq[tid + st]; }
        __syncthreads();
    }
    if (tid == 0) {
        double cnt = (double)BB * NN;
        double mean = ssum[0] / cnt;
        double var = ssq[0] / cnt - mean * mean;
        float inv = rsqrtf((float)var + EPSF);
        float sc = g[d] * inv;
        scale[d] = sc;
        shift[d] = bb[d] - (float)mean * sc;
    }
}

// tokens from bf16 y5
__global__ void pool_bf16_kernel(const bf16_t* __restrict__ y5, const float* __restrict__ scale,
                                 const float* __restrict__ shift, const float* __restrict__ cls,
                                 float* __restrict__ t) {
    int gid = blockIdx.x * blockDim.x + threadIdx.x;
    if (gid >= BB * TOK * DD) return;
    int d = gid % DD; int l = (gid / DD) % TOK; int b = gid / (DD * TOK);
    float v;
    if (l == 0) {
        v = cls[d];
    } else {
        int pp = l - 1;
        const bf16_t* row = y5 + ((long)b * DD + d) * NN + pp * PSZ;
        float sc = scale[d], sh = shift[d];
        float m = -INFINITY;
        for (int i = 0; i < PSZ; ++i) {
            float u = (float)row[i] * sc + sh;
            u = (u >= 0.f) ? u : 0.2f * u;
            m = fmaxf(m, u);
        }
        v = m;
    }
    t[gid] = v;
}

// LN: fp32 stats over t (+pos in-place), bf16 normalized output (GEMM A operand)
__global__ __launch_bounds__(256) void ln_kernel(float* __restrict__ t, const float* __restrict__ pos,
                                                 const float* __restrict__ g, const float* __restrict__ bb,
                                                 bf16_t* __restrict__ hn, int addpos) {
    __shared__ double s1[256], s2[256];
    long r = blockIdx.x;
    int tid = threadIdx.x;
    float vals[4];
    double s = 0.0, sq = 0.0;
    for (int i = 0; i < 4; ++i) {
        int d = tid + i * 256;
        float v = t[r * DD + d];
        if (addpos) { v += pos[r * DD + d]; t[r * DD + d] = v; }
        vals[i] = v; s += v; sq += (double)v * v;
    }
    s1[tid] = s; s2[tid] = sq;
    __syncthreads();
    for (int st = 128; st > 0; st >>= 1) {
        if (tid < st) { s1[tid] += s1[tid + st]; s2[tid] += s2[tid + st]; }
        __syncthreads();
    }
    double mean = s1[0] / DD;
    float var = (float)(s2[0] / DD - mean * mean);
    float fm = (float)mean;
    float inv = rsqrtf(var + EPSF);
    for (int i = 0; i < 4; ++i) {
        int d = tid + i * 256;
        hn[r * DD + d] = (bf16_t)((vals[i] - fm) * inv * g[d] + bb[d]);
    }
}

__global__ __launch_bounds__(256) void attn_kernel(const float* __restrict__ qkv, bf16_t* __restrict__ z) {
    __shared__ float ks[TOK][DHH + 1];
    __shared__ float vs[TOK][DHH + 1];
    __shared__ float ss[TOK][TOK];
    int bh = blockIdx.x;
    int b = bh / HH, h = bh % HH;
    int tid = threadIdx.x;
    for (int i = tid; i < TOK * DHH; i += 256) {
        int l = i / DHH, d = i % DHH;
        long base = (long)(b * TOK + l) * 1536;
        ks[l][d] = qkv[base + 512 + h * DHH + d];
        vs[l][d] = qkv[base + 1024 + h * DHH + d];
    }
    __syncthreads();
    for (int i = tid; i < TOK * TOK; i += 256) {
        int l = i / TOK, m = i % TOK;
        const float* qrow = qkv + (long)(b * TOK + l) * 1536 + h * DHH;
        float acc = 0.f;
        for (int d = 0; d < DHH; ++d) acc += qrow[d] * ks[m][d];
        ss[l][m] = acc * 0.125f;
    }
    __syncthreads();
    if (tid < TOK) {
        float mx = -INFINITY;
        for (int m = 0; m < TOK; ++m) mx = fmaxf(mx, ss[tid][m]);
        float sum = 0.f;
        for (int m = 0; m < TOK; ++m) { float e = expf(ss[tid][m] - mx); ss[tid][m] = e; sum += e; }
        float invs = 1.f / sum;
        for (int m = 0; m < TOK; ++m) ss[tid][m] *= invs;
    }
    __syncthreads();
    for (int i = tid; i < TOK * DHH; i += 256) {
        int l = i / DHH, d = i % DHH;
        float acc = 0.f;
        for (int m = 0; m < TOK; ++m) acc += ss[l][m] * vs[m][d];
        z[(long)(b * TOK + l) * INNER_ + h * DHH + d] = (bf16_t)acc;
    }
}

__global__ void final_kernel(const float* __restrict__ t, float* __restrict__ out) {
    int gid = blockIdx.x * blockDim.x + threadIdx.x;
    if (gid >= BB * PP * DD) return;
    int d = gid % DD; int p = (gid / DD) % PP; int b = gid / (DD * PP);
    out[gid] = t[((long)b * TOK + 1 + p) * DD + d];
}

static inline int ceil_div(long a, long b) { return (int)((a + b - 1) / b); }

extern "C" void kernel_launch(void* const* d_in, const int* in_sizes, int n_in,
                              void* d_out, int out_size, void* d_ws, size_t ws_size,
                              hipStream_t stream) {
    const float* x    = (const float*)d_in[0];
    const float* pos  = (const float*)d_in[1];
    const float* w1   = (const float*)d_in[2];
    const float* g1   = (const float*)d_in[3];
    const float* b1   = (const float*)d_in[4];
    const float* w2   = (const float*)d_in[5];
    const float* g2   = (const float*)d_in[6];
    const float* b2   = (const float*)d_in[7];
    const float* w3   = (const float*)d_in[8];
    const float* g3   = (const float*)d_in[9];
    const float* b3   = (const float*)d_in[10];
    const float* w4   = (const float*)d_in[11];
    const float* g4   = (const float*)d_in[12];
    const float* b4   = (const float*)d_in[13];
    const float* w5   = (const float*)d_in[14];
    const float* g5   = (const float*)d_in[15];
    const float* b5   = (const float*)d_in[16];
    const float* cls  = (const float*)d_in[17];
    const float* ln1g = (const float*)d_in[18];
    const float* ln1b = (const float*)d_in[19];
    const float* wqkv = (const float*)d_in[20];
    const float* wout = (const float*)d_in[21];
    const float* bout = (const float*)d_in[22];
    const float* ln2g = (const float*)d_in[23];
    const float* ln2b = (const float*)d_in[24];
    const float* wff1 = (const float*)d_in[25];
    const float* bff1 = (const float*)d_in[26];
    const float* wff2 = (const float*)d_in[27];
    const float* bff2 = (const float*)d_in[28];
    float* out = (float*)d_out;

    // ---- workspace layout ----
    char* ws = (char*)d_ws;
    size_t off = 0;
    auto alloc = [&](size_t bytes) -> char* {
        char* ptr = ws + off;
        off = (off + bytes + 255) & ~(size_t)255;
        return ptr;
    };
    float*  h      = (float*)alloc((size_t)BB * 512 * NN * 4);   // 33.5 MB; reused as y5 BF16 later
    float*  t      = (float*)alloc((size_t)BB * TOK * DD * 4);
    bf16_t* hnb    = (bf16_t*)alloc((size_t)BB * TOK * DD * 4);
    float*  qkvb   = (float*)alloc((size_t)BB * TOK * 1536 * 4);
    bf16_t* zbb    = (bf16_t*)alloc((size_t)BB * TOK * INNER_ * 4);
    bf16_t* ubb    = (bf16_t*)alloc((size_t)BB * TOK * MLPD * 4);
    double* dsum   = (double*)alloc(1024 * 8);
    double* dsq    = (double*)alloc(1024 * 8);
    float*  scaleb = (float*)alloc(1024 * 4);
    float*  shiftb = (float*)alloc(1024 * 4);
    size_t ubase = off;

    // union view 1 (conv phase): pts, xx, idxb, pbuf, qbuf, dist
    size_t uoff = ubase;
    auto ualloc = [&](size_t bytes) -> char* {
        char* ptr = ws + uoff;
        uoff = (uoff + bytes + 255) & ~(size_t)255;
        return ptr;
    };
    float* pts  = (float*)ualloc((size_t)BB * 3 * NN * 4);
    float* xx   = (float*)ualloc((size_t)BB * NN * 4);
    int*   idxb = (int*)  ualloc((size_t)BB * NN * KK * 4);
    float* pbuf = (float*)ualloc((size_t)BB * NN * 256 * 4);
    float* qbuf = (float*)ualloc((size_t)BB * NN * 256 * 4);
    size_t dist_rel = uoff - ubase;
    float* distb = (float*)(ws + uoff);
    // maxb/minb alias the dist buffer (dist is dead after topk); full mode only.
    float* maxb  = distb;
    float* minb  = distb + (size_t)BB * NN * 256;

    // union view 2 (stage 3/4, bf16 path): hT + transposed/converted bf16 weights
    size_t voff = ubase;
    auto valloc = [&](size_t bytes) -> char* {
        char* ptr = ws + voff;
        voff = (voff + bytes + 255) & ~(size_t)255;
        return ptr;
    };
    bf16_t* hT     = (bf16_t*)valloc((size_t)BB * NN * 512 * 2);
    bf16_t* wTqkv  = (bf16_t*)valloc((size_t)DEPTH_ * 1536 * DD * 2);
    bf16_t* wTout  = (bf16_t*)valloc((size_t)DEPTH_ * DD * INNER_ * 2);
    bf16_t* wTff1  = (bf16_t*)valloc((size_t)DEPTH_ * MLPD * DD * 2);
    bf16_t* wTff2  = (bf16_t*)valloc((size_t)DEPTH_ * DD * MLPD * 2);
    bf16_t* w5b    = (bf16_t*)valloc((size_t)DD * 512 * 2);
    size_t stage_bf16 = voff - ubase;

    size_t conv_full  = dist_rel + (size_t)BB * NN * NN * 4;
    size_t conv_batch = dist_rel + (size_t)NN * NN * 4;

    auto mx = [](size_t a, size_t b) { return a > b ? a : b; };
    bool use_bf16 = ws_size >= ubase + mx(conv_batch, stage_bf16);
    bool full     = ws_size >= ubase + mx(conv_full, stage_bf16);
    if (!use_bf16) return;  // insufficient scratch
    bf16_t* y5bf = (bf16_t*)h;                           // 32 MB fits in h's 33.5 MB slot

    // ---- stage 1: transpose points ----
    transpose_x_kernel<<<ceil_div((long)BB * NN * 3, 256), 256, 0, stream>>>(x, pts);

    // ---- stage 2: four EdgeConv blocks ----
    const int NTRI = 136;   // 16*17/2 upper-triangle 128x128 tiles
    auto run_conv = [&](const float* xin, int xbs, int C, const float* w,
                        const float* g, const float* bb, float* hout, int O) {
        sqnorm_kernel<<<ceil_div((long)BB * NN, 256), 256, 0, stream>>>(xin, xbs, C, xx);
        if (full) {
            dist_kernel<<<dim3(NTRI, 1, BB), 256, 0, stream>>>(xin, xbs, C, xx, 0, distb);
            topk_kernel<<<dim3(NN / 4, BB), 256, 0, stream>>>(distb, 0, idxb);
        } else {
            for (int b = 0; b < BB; ++b) {
                dist_kernel<<<dim3(NTRI, 1, 1), 256, 0, stream>>>(xin, xbs, C, xx, b, distb);
                topk_kernel<<<dim3(NN / 4, 1), 256, 0, stream>>>(distb, b, idxb);
            }
        }
        {
            dim3 grid(NN / 32, O / 32, BB);
            pq_kernel<<<grid, 256, 0, stream>>>(xin, xbs, C, w, O, pbuf, qbuf);
        }
        zero_stats_kernel<<<4, 256, 0, stream>>>(dsum, dsq);
        if (full) {
            edge_gather_kernel<<<256, 256, 0, stream>>>(pbuf, qbuf, idxb, O, dsum, dsq, maxb, minb);
            bn_finalize_kernel<<<1, 256, 0, stream>>>(dsum, dsq, g, bb, O, (double)BB * NN * KK, scaleb, shiftb);
            edge_finalize_kernel<<<dim3(NN / 32, O / 32, BB), 256, 0, stream>>>(
                maxb, minb, O, scaleb, shiftb, hout, 512 * NN);
        } else {
            edge_stats_kernel<<<256, 256, 0, stream>>>(pbuf, qbuf, idxb, O, dsum, dsq);
            bn_finalize_kernel<<<1, 256, 0, stream>>>(dsum, dsq, g, bb, O, (double)BB * NN * KK, scaleb, shiftb);
            edge_out_kernel<<<ceil_div((long)BB * NN * O, 256), 256, 0, stream>>>(
                pbuf, qbuf, idxb, O, scaleb, shiftb, hout, 512 * NN);
        }
    };
    run_conv(pts, 3 * NN, 3, w1, g1, b1, h, 64);
    run_conv(h, 512 * NN, 64, w2, g2, b2, h + 64 * NN, 64);
    run_conv(h + 64 * NN, 512 * NN, 64, w3, g3, b3, h + 128 * NN, 128);
    run_conv(h + 128 * NN, 512 * NN, 128, w4, g4, b4, h + 256 * NN, 256);

    const int M = BB * TOK;  // 520 rows

    // ---- transposes/converts: h -> hT (bf16), weights -> [N][K] bf16, w5 -> bf16 ----
    transpose_cvt_kernel<<<dim3(NN / 32, 512 / 32, BB), 256, 0, stream>>>(
        h, hT, 512, NN, (long)512 * NN, (long)NN * 512);
    transpose_cvt_kernel<<<dim3(1536 / 32, DD / 32, DEPTH_), 256, 0, stream>>>(
        wqkv, wTqkv, DD, 1536, (long)DD * 1536, (long)1536 * DD);
    transpose_cvt_kernel<<<dim3(DD / 32, INNER_ / 32, DEPTH_), 256, 0, stream>>>(
        wout, wTout, INNER_, DD, (long)INNER_ * DD, (long)DD * INNER_);
    transpose_cvt_kernel<<<dim3(MLPD / 32, DD / 32, DEPTH_), 256, 0, stream>>>(
        wff1, wTff1, DD, MLPD, (long)DD * MLPD, (long)MLPD * DD);
    transpose_cvt_kernel<<<dim3(DD / 32, MLPD / 32, DEPTH_), 256, 0, stream>>>(
        wff2, wTff2, MLPD, DD, (long)MLPD * DD, (long)DD * MLPD);
    cvt_bf16_kernel<<<ceil_div((long)DD * 512 / 8, 256), 256, 0, stream>>>(w5, w5b, (long)DD * 512 / 8);

    // ---- stage 3: conv5 (MFMA, bf16 out into h's slot) + BN + pool ----
    gemm_bf16_kernel<<<dim3(NN / 64, DD / 64, BB), 256, 0, stream>>>(
        w5b, hT, nullptr, (float*)y5bf, DD, 512, NN, 0L, (long)NN * 512, (long)DD * NN, GEMM_OUTBF16);
    bn5_stats_bf16_kernel<<<DD, 256, 0, stream>>>(y5bf, g5, b5, scaleb, shiftb);
    pool_bf16_kernel<<<ceil_div((long)BB * TOK * DD, 256), 256, 0, stream>>>(y5bf, scaleb, shiftb, cls, t);

    // ---- stage 4: transformer (MFMA GEMMs, bf16 A operands everywhere) ----
    for (int i = 0; i < DEPTH_; ++i) {
        ln_kernel<<<M, 256, 0, stream>>>(t, pos, ln1g + i * DD, ln1b + i * DD, hnb, 1);
        gemm_bf16_kernel<<<dim3(1536 / 64, ceil_div(M, 64), 1), 256, 0, stream>>>(
            hnb, wTqkv + (size_t)i * 1536 * DD, nullptr, qkvb, M, DD, 1536, 0L, 0L, 0L, 0);
        attn_kernel<<<BB * HH, 256, 0, stream>>>(qkvb, zbb);
        gemm_bf16_kernel<<<dim3(DD / 64, ceil_div(M, 64), 1), 256, 0, stream>>>(
            zbb, wTout + (size_t)i * DD * INNER_, bout + i * DD, t, M, INNER_, DD, 0L, 0L, 0L, GEMM_ACC);
        ln_kernel<<<M, 256, 0, stream>>>(t, nullptr, ln2g + i * DD, ln2b + i * DD, hnb, 0);
        gemm_bf16_kernel<<<dim3(MLPD / 64, ceil_div(M, 64), 1), 256, 0, stream>>>(
            hnb, wTff1 + (size_t)i * MLPD * DD, bff1 + i * MLPD, (float*)ubb, M, DD, MLPD,
            0L, 0L, 0L, GEMM_GELU | GEMM_OUTBF16);
        gemm_bf16_kernel<<<dim3(DD / 64, ceil_div(M, 64), 1), 256, 0, stream>>>(
            ubb, wTff2 + (size_t)i * DD * MLPD, bff2 + i * DD, t, M, MLPD, DD, 0L, 0L, 0L, GEMM_ACC);
    }

    // ---- stage 5: output t[:,1:] ----
    final_kernel<<<ceil_div((long)BB * PP * DD, 256), 256, 0, stream>>>(t, out);
}

// Round 6
// 2000.227 us; speedup vs baseline: 1.0607x; 1.0607x over previous
//
#include <hip/hip_runtime.h>
#include <math.h>

// ---- problem constants ----
#define BB 8
#define NN 2048
#define PSZ 32
#define PP 64
#define DD 1024
#define MLPD 2048
#define DEPTH_ 6
#define HH 8
#define DHH 64
#define INNER_ 512
#define KK 20
#define TOK 65
#define EPSF 1e-5f

#define GEMM_ACC 1
#define GEMM_GELU 2
#define GEMM_OUTBF16 4

typedef __bf16 bf16_t;
typedef __attribute__((ext_vector_type(8))) __bf16 bf16x8;
typedef __attribute__((ext_vector_type(4))) float f32x4;

// async global->LDS 16B: HW writes lds_base(wave-uniform) + lane*16
__device__ __forceinline__ void async_copy16(const bf16_t* gsrc, bf16_t* ldst) {
    __builtin_amdgcn_global_load_lds(
        (const __attribute__((address_space(1))) unsigned int*)gsrc,
        (__attribute__((address_space(3))) unsigned int*)ldst,
        16, 0, 0);
}

// x [B,N,3] -> pts [B,3,N]
__global__ void transpose_x_kernel(const float* __restrict__ x, float* __restrict__ pts) {
    int gid = blockIdx.x * blockDim.x + threadIdx.x;
    if (gid >= BB * NN * 3) return;
    int c = gid % 3; int n = (gid / 3) % NN; int b = gid / (3 * NN);
    pts[(b * 3 + c) * NN + n] = x[gid];
}

// xx[b,n] = sum_c x[b,c,n]^2
__global__ void sqnorm_kernel(const float* __restrict__ x, int bs, int C, float* __restrict__ xx) {
    int gid = blockIdx.x * blockDim.x + threadIdx.x;
    if (gid >= BB * NN) return;
    int n = gid % NN; int b = gid / NN;
    const float* xp = x + b * bs + n;
    float s = 0.f;
    for (int c = 0; c < C; ++c) { float v = xp[c * NN]; s += v * v; }
    xx[gid] = s;
}

// dist[n,m] = 2*sum_c x[c,n]x[c,m] - xx[n] - xx[m]  (symmetric)
// Upper-triangle tile grid: 136 of 256 128x128 tiles per batch; off-diagonal
// tiles mirror via LDS transpose (write volume unchanged, compute 0.53x).
__global__ __launch_bounds__(256) void dist_kernel(const float* __restrict__ x, int bs, int C,
                                                   const float* __restrict__ xx, int b0,
                                                   float* __restrict__ dist) {
    __shared__ __align__(16) float smem[4224];   // As[16][132] + Bs[16][132]  ==  tb[32][132]
    float (*As)[132] = (float(*)[132])smem;
    float (*Bs)[132] = (float(*)[132])(smem + 16 * 132);
    float (*tb)[132] = (float(*)[132])smem;

    // triangular decode: blockIdx.x in [0,136) -> (bi,bj), bi <= bj
    int q = blockIdx.x;
    int bi = 0, rem = q;
    while (rem >= (16 - bi)) { rem -= (16 - bi); ++bi; }
    int bj = bi + rem;

    int b = b0 + blockIdx.z;
    int n0 = bi * 128, m0 = bj * 128;
    int tid = threadIdx.x;
    int ty = tid >> 4, tx = tid & 15;
    float acc[2][2][4][4] = {};
    const float* xb = x + (long)b * bs;
    for (int k0 = 0; k0 < C; k0 += 16) {
        #pragma unroll
        for (int p = 0; p < 2; ++p) {
            int li = tid + p * 256;        // 0..511 float4-chunks
            int i4 = li & 31;              // float4 index within 128-wide row
            int kk = li >> 5;              // 0..15
            int c = k0 + kk;
            float4 va = make_float4(0.f, 0.f, 0.f, 0.f);
            float4 vb = va;
            if (c < C) {
                va = *(const float4*)&xb[(long)c * NN + n0 + i4 * 4];
                vb = *(const float4*)&xb[(long)c * NN + m0 + i4 * 4];
            }
            *(float4*)&As[kk][i4 * 4] = va;
            *(float4*)&Bs[kk][i4 * 4] = vb;
        }
        __syncthreads();
        #pragma unroll
        for (int kk = 0; kk < 16; ++kk) {
            float a[2][4], bv[2][4];
            *(float4*)a[0] = *(const float4*)&As[kk][ty * 4];
            *(float4*)a[1] = *(const float4*)&As[kk][64 + ty * 4];
            *(float4*)bv[0] = *(const float4*)&Bs[kk][tx * 4];
            *(float4*)bv[1] = *(const float4*)&Bs[kk][64 + tx * 4];
            #pragma unroll
            for (int ri = 0; ri < 2; ++ri)
                #pragma unroll
                for (int ci = 0; ci < 2; ++ci)
                    #pragma unroll
                    for (int i = 0; i < 4; ++i)
                        #pragma unroll
                        for (int j = 0; j < 4; ++j)
                            acc[ri][ci][i][j] += a[ri][i] * bv[ci][j];
        }
        __syncthreads();
    }
    float* db = dist + (long)blockIdx.z * NN * NN;
    const float* xxb = xx + b * NN;
    float xm[2][4];
    #pragma unroll
    for (int ci = 0; ci < 2; ++ci)
        #pragma unroll
        for (int j = 0; j < 4; ++j)
            xm[ci][j] = xxb[m0 + ci * 64 + tx * 4 + j];
    #pragma unroll
    for (int ri = 0; ri < 2; ++ri)
        #pragma unroll
        for (int i = 0; i < 4; ++i) {
            float xn = xxb[n0 + ri * 64 + ty * 4 + i];
            #pragma unroll
            for (int ci = 0; ci < 2; ++ci)
                #pragma unroll
                for (int j = 0; j < 4; ++j)
                    acc[ri][ci][i][j] = 2.f * acc[ri][ci][i][j] - xn - xm[ci][j];
        }
    // direct tile write
    #pragma unroll
    for (int ri = 0; ri < 2; ++ri)
        #pragma unroll
        for (int i = 0; i < 4; ++i) {
            int n = n0 + ri * 64 + ty * 4 + i;
            #pragma unroll
            for (int ci = 0; ci < 2; ++ci)
                *(float4*)&db[(long)n * NN + m0 + ci * 64 + tx * 4] = *(float4*)&acc[ri][ci][i][0];
        }
    // mirror tile write via LDS transpose, 4 slabs of 32 rows
    if (bi != bj) {
        #pragma unroll
        for (int s = 0; s < 4; ++s) {
            __syncthreads();
            int ci = s >> 1;
            if ((tx >> 3) == (s & 1)) {
                #pragma unroll
                for (int ri = 0; ri < 2; ++ri)
                    #pragma unroll
                    for (int j = 0; j < 4; ++j) {
                        float4 v;
                        v.x = acc[ri][ci][0][j];
                        v.y = acc[ri][ci][1][j];
                        v.z = acc[ri][ci][2][j];
                        v.w = acc[ri][ci][3][j];
                        *(float4*)&tb[(tx & 7) * 4 + j][ri * 64 + ty * 4] = v;
                    }
            }
            __syncthreads();
            int r = tid >> 3;              // 0..31
            int c0 = (tid & 7) * 16;       // 0..112
            long orow = (long)(m0 + s * 32 + r) * NN + n0 + c0;
            #pragma unroll
            for (int c4 = 0; c4 < 4; ++c4)
                *(float4*)&db[orow + c4 * 4] = *(const float4*)&tb[r][c0 + c4 * 4];
        }
    }
}

// one WAVE per row of 2048. Exact top-20 via threshold + compact + bitonic.
__global__ __launch_bounds__(256) void topk_kernel(const float* __restrict__ dist, int b0,
                                                   int* __restrict__ idx) {
    __shared__ float cval[4][64];
    __shared__ int   cidx[4][64];
    int b = b0 + blockIdx.y;
    int wid = threadIdx.x >> 6, lane = threadIdx.x & 63;
    int n = blockIdx.x * 4 + wid;
    const float* row = dist + ((long)blockIdx.y * NN + n) * NN;
    float vals[32];
    #pragma unroll
    for (int s = 0; s < 32; ++s) vals[s] = row[s * 64 + lane];
    int* op = idx + ((long)b * NN + n) * KK;

    float lm = vals[0];
    #pragma unroll
    for (int s = 1; s < 32; ++s) lm = fmaxf(lm, vals[s]);

    float sv = lm;
    #pragma unroll
    for (int k = 2; k <= 64; k <<= 1) {
        #pragma unroll
        for (int j = k >> 1; j > 0; j >>= 1) {
            float pv = __shfl_xor(sv, j);
            bool lower = (lane & j) == 0;
            bool up = (lane & k) != 0;
            bool ownBetter = sv > pv;
            bool keepOwn = ownBetter ^ (lower == up);
            sv = keepOwn ? sv : pv;
        }
    }
    float t = __shfl(sv, 19);   // 20th largest lane-max

    int base = 0;
    #pragma unroll
    for (int s = 0; s < 32; ++s) {
        bool q = vals[s] >= t;
        unsigned long long m = __ballot(q);
        int my = base + (int)__builtin_amdgcn_mbcnt_hi((unsigned)(m >> 32),
                         __builtin_amdgcn_mbcnt_lo((unsigned)m, 0u));
        if (q && my < 64) { cval[wid][my] = vals[s]; cidx[wid][my] = s * 64 + lane; }
        base += (int)__popcll(m);
    }
    __asm__ volatile("s_waitcnt lgkmcnt(0)" ::: "memory");

    if (base <= 64) {
        float v = (lane < base) ? cval[wid][lane] : -INFINITY;
        int   ii = (lane < base) ? cidx[wid][lane] : 0x7FFFFFFF;
        #pragma unroll
        for (int k = 2; k <= 64; k <<= 1) {
            #pragma unroll
            for (int j = k >> 1; j > 0; j >>= 1) {
                float pv = __shfl_xor(v, j);
                int   pi = __shfl_xor(ii, j);
                bool lower = (lane & j) == 0;
                bool up = (lane & k) != 0;
                bool ownBetter = (v > pv) || (v == pv && ii < pi);
                bool keepOwn = ownBetter ^ (lower == up);
                if (!keepOwn) { v = pv; ii = pi; }
            }
        }
        if (lane < KK) op[lane] = ii;
    } else {
        for (int kk = 0; kk < KK; ++kk) {
            float bv = vals[0]; int bsl = 0;
            #pragma unroll
            for (int s = 1; s < 32; ++s) if (vals[s] > bv) { bv = vals[s]; bsl = s; }
            int bm = bsl * 64 + lane;
            for (int off = 32; off; off >>= 1) {
                float ov = __shfl_xor(bv, off);
                int om = __shfl_xor(bm, off);
                if (ov > bv || (ov == bv && om < bm)) { bv = ov; bm = om; }
            }
            int wslot = bm >> 6, wlane = bm & 63;
            #pragma unroll
            for (int s = 0; s < 32; ++s)
                if (s == wslot) vals[s] = (lane == wlane) ? -INFINITY : vals[s];
            if (lane == 0) op[kk] = bm;
        }
    }
}

// p/q (fp32, LDS tiled)
__global__ __launch_bounds__(256) void pq_kernel(const float* __restrict__ x, int bs, int C,
                                                 const float* __restrict__ w, int O,
                                                 float* __restrict__ p, float* __restrict__ q) {
    __shared__ float wT[256][33];
    __shared__ float xs[128][32];
    int b = blockIdx.z;
    int o0 = blockIdx.y * 32;
    int n0 = blockIdx.x * 32;
    int tid = threadIdx.x;
    for (int i = tid; i < 2 * C * 32; i += 256) {
        int c2 = i % (2 * C), o = i / (2 * C);
        wT[c2][o] = w[(o0 + o) * 2 * C + c2];
    }
    for (int i = tid; i < C * 32; i += 256) {
        int nl = i % 32, c = i / 32;
        xs[c][nl] = x[b * bs + c * NN + n0 + nl];
    }
    __syncthreads();
    int o_l = tid & 31;
    int n_base = (tid >> 5) * 4;
    float ps[4] = {0.f, 0.f, 0.f, 0.f};
    float qs[4] = {0.f, 0.f, 0.f, 0.f};
    for (int c = 0; c < C; ++c) {
        float4 xv = *(const float4*)&xs[c][n_base];
        float wa = wT[c][o_l];
        float wb = wT[C + c][o_l];
        float d = wb - wa;
        ps[0] += xv.x * wa; qs[0] += xv.x * d;
        ps[1] += xv.y * wa; qs[1] += xv.y * d;
        ps[2] += xv.z * wa; qs[2] += xv.z * d;
        ps[3] += xv.w * wa; qs[3] += xv.w * d;
    }
    for (int j = 0; j < 4; ++j) {
        long r = (long)(b * NN + n0 + n_base + j) * O + o0 + o_l;
        p[r] = ps[j];
        q[r] = qs[j];
    }
}

__global__ void zero_stats_kernel(double* __restrict__ s1, double* __restrict__ s2) {
    int t = blockIdx.x * blockDim.x + threadIdx.x;
    if (t < 1024) { s1[t] = 0.0; s2[t] = 0.0; }
}

// FUSED gather, HIGH-PARALLELISM (2048 blocks = 8 rows/block): one pass computes
// BN stats (LDS-reduced, one atomic per o per block) AND per-(row,o) max/min
// (coalesced into maxb/minb).
__global__ __launch_bounds__(256) void edge_gather_kernel(const float* __restrict__ p,
                                                          const float* __restrict__ q,
                                                          const int* __restrict__ idx, int O,
                                                          double* __restrict__ gsum,
                                                          double* __restrict__ gsumsq,
                                                          float* __restrict__ maxb,
                                                          float* __restrict__ minb) {
    __shared__ double ls[256], lss[256];
    int tid = threadIdx.x;
    int o = tid % O;
    int grp = tid / O;
    int ngrp = 256 / O;
    int rows_per_blk = (BB * NN) / gridDim.x;
    int r0 = blockIdx.x * rows_per_blk;
    double s = 0.0, ss = 0.0;
    for (int r = r0 + grp; r < r0 + rows_per_blk; r += ngrp) {
        int b = r / NN;
        float qv = q[(long)r * O + o];
        const int* ip = idx + (long)r * KK;
        float mx = -INFINITY, mn = INFINITY;
        for (int k = 0; k < KK; ++k) {
            int j = ip[k];
            float v = p[(long)(b * NN + j) * O + o] + qv;
            s += v; ss += (double)v * v;
            mx = fmaxf(mx, v); mn = fminf(mn, v);
        }
        maxb[(long)r * O + o] = mx;
        minb[(long)r * O + o] = mn;
    }
    ls[tid] = s; lss[tid] = ss;
    __syncthreads();
    if (grp == 0) {
        for (int g2 = 1; g2 < ngrp; ++g2) { s += ls[g2 * O + o]; ss += lss[g2 * O + o]; }
        atomicAdd(&gsum[o], s);
        atomicAdd(&gsumsq[o], ss);
    }
}

__global__ void bn_finalize_kernel(const double* __restrict__ gsum, const double* __restrict__ gsumsq,
                                   const float* __restrict__ g, const float* __restrict__ bb, int O, double cnt,
                                   float* __restrict__ scale, float* __restrict__ shift) {
    int o = blockIdx.x * blockDim.x + threadIdx.x;
    if (o >= O) return;
    double mean = gsum[o] / cnt;
    double var = gsumsq[o] / cnt - mean * mean;
    float inv = rsqrtf((float)var + EPSF);
    float sc = g[o] * inv;
    scale[o] = sc;
    shift[o] = bb[o] - (float)mean * sc;
}

// elementwise finalize: out[b][o][n] = lrelu(sc*(sc>=0?max:min)+sh), LDS-transposed
// (monotone lrelu => max over k commutes with the affine BN map; sign picks max/min)
__global__ __launch_bounds__(256) void edge_finalize_kernel(const float* __restrict__ maxb,
                                                            const float* __restrict__ minb, int O,
                                                            const float* __restrict__ scale,
                                                            const float* __restrict__ shift,
                                                            float* __restrict__ out, int obs) {
    __shared__ float tile[32][33];
    int b = blockIdx.z;
    int o0 = blockIdx.y * 32, n0 = blockIdx.x * 32;
    int tx = threadIdx.x & 31, tg = threadIdx.x >> 5;
    float sc = scale[o0 + tx], sh = shift[o0 + tx];
    for (int i = 0; i < 4; ++i) {
        int n = tg + i * 8;
        long rr = (long)(b * NN + n0 + n) * O + o0 + tx;
        float base = (sc >= 0.f) ? maxb[rr] : minb[rr];
        float a = sc * base + sh;
        tile[n][tx] = (a >= 0.f) ? a : 0.2f * a;
    }
    __syncthreads();
    for (int i = 0; i < 4; ++i) {
        int o = tg + i * 8;
        out[(long)b * obs + (long)(o0 + o) * NN + n0 + tx] = tile[tx][o];
    }
}

// legacy two-pass path (tight-workspace mode only)
__global__ __launch_bounds__(256) void edge_stats_kernel(const float* __restrict__ p, const float* __restrict__ q,
                                                         const int* __restrict__ idx, int O,
                                                         double* __restrict__ gsum, double* __restrict__ gsumsq) {
    int tid = threadIdx.x;
    int o = tid % O;
    int grp = tid / O;
    int ngrp = 256 / O;
    int rows_per_blk = (BB * NN) / gridDim.x;
    int r0 = blockIdx.x * rows_per_blk;
    double s = 0.0, ss = 0.0;
    for (int r = r0 + grp; r < r0 + rows_per_blk; r += ngrp) {
        int b = r / NN;
        float qv = q[r * O + o];
        for (int k = 0; k < KK; ++k) {
            int j = idx[r * KK + k];
            float v = p[(b * NN + j) * O + o] + qv;
            s += v; ss += (double)v * v;
        }
    }
    atomicAdd(&gsum[o], s);
    atomicAdd(&gsumsq[o], ss);
}

__global__ void edge_out_kernel(const float* __restrict__ p, const float* __restrict__ q,
                                const int* __restrict__ idx, int O,
                                const float* __restrict__ scale, const float* __restrict__ shift,
                                float* __restrict__ out, int obs) {
    int gid = blockIdx.x * blockDim.x + threadIdx.x;
    if (gid >= BB * NN * O) return;
    int o = gid % O; int n = (gid / O) % NN; int b = gid / (O * NN);
    int r = b * NN + n;
    float qv = q[r * O + o];
    float sc = scale[o], sh = shift[o];
    float m = -INFINITY;
    for (int k = 0; k < KK; ++k) {
        int j = idx[r * KK + k];
        float v = (p[(b * NN + j) * O + o] + qv) * sc + sh;
        v = (v >= 0.f) ? v : 0.2f * v;
        m = fmaxf(m, v);
    }
    out[b * obs + o * NN + n] = m;
}

// transpose + fp32->bf16: in [R][C] -> out [C][R] bf16, batched in z
__global__ __launch_bounds__(256) void transpose_cvt_kernel(const float* __restrict__ in,
                                                            bf16_t* __restrict__ outp,
                                                            int R, int C, long s_in, long s_out) {
    __shared__ float tile[32][33];
    const float* ib = in + (long)blockIdx.z * s_in;
    bf16_t* ob = outp + (long)blockIdx.z * s_out;
    int r0 = blockIdx.y * 32, c0 = blockIdx.x * 32;
    int tx = threadIdx.x & 31, tg = threadIdx.x >> 5;
    for (int i = 0; i < 4; ++i) {
        int r = tg + i * 8;
        tile[r][tx] = ib[(long)(r0 + r) * C + c0 + tx];
    }
    __syncthreads();
    for (int i = 0; i < 4; ++i) {
        int c = tg + i * 8;
        ob[(long)(c0 + c) * R + r0 + tx] = (bf16_t)tile[tx][c];
    }
}

// elementwise fp32 -> bf16 (8 per thread)
__global__ void cvt_bf16_kernel(const float* __restrict__ in, bf16_t* __restrict__ outp, long n8) {
    long g = (long)blockIdx.x * blockDim.x + threadIdx.x;
    if (g >= n8) return;
    const float4* pp = (const float4*)(in + g * 8);
    float4 a = pp[0], b = pp[1];
    bf16x8 v;
    v[0] = (bf16_t)a.x; v[1] = (bf16_t)a.y; v[2] = (bf16_t)a.z; v[3] = (bf16_t)a.w;
    v[4] = (bf16_t)b.x; v[5] = (bf16_t)b.y; v[6] = (bf16_t)b.z; v[7] = (bf16_t)b.w;
    *(bf16x8*)(outp + g * 8) = v;
}

// bf16 MFMA GEMM: out[M,N] = A[M,K] x Bt[N,K]^T   (A and Bt both bf16)
// 64x64 tile, BK=32, 4 waves each computing a 32x32 quadrant via 2x2 mfma_16x16x32.
// Both operands staged via global_load_lds width-16.
__global__ __launch_bounds__(256) void gemm_bf16_kernel(const bf16_t* __restrict__ A,
                                                        const bf16_t* __restrict__ Bt,
                                                        const float* __restrict__ bias,
                                                        float* __restrict__ out,
                                                        int M, int Kd, int Nd,
                                                        long sA, long sBt, long sO, int flags) {
    __shared__ __align__(16) bf16_t As[64 * 32];
    __shared__ __align__(16) bf16_t Bs[64 * 32];
    const bf16_t* Ab = A + (long)blockIdx.z * sA;
    const bf16_t* Bb = Bt + (long)blockIdx.z * sBt;
    int row0 = blockIdx.y * 64, col0 = blockIdx.x * 64;
    int tid = threadIdx.x;
    int lane = tid & 63, wv = tid >> 6;
    int wm = wv >> 1, wn = wv & 1;
    int srow = tid & 63;
    int sk = wv * 8;
    const bf16_t* ap = Ab + (long)(row0 + srow) * Kd + sk;
    const bf16_t* bp = Bb + (long)(col0 + srow) * Kd + sk;
    bf16_t* lA = &As[wv * 512];
    bf16_t* lB = &Bs[wv * 512];
    f32x4 acc[2][2] = {};
    for (int k0 = 0; k0 < Kd; k0 += 32) {
        async_copy16(ap + k0, lA);
        async_copy16(bp + k0, lB);
        __syncthreads();
        int q = lane >> 4, cl = lane & 15;
        bf16x8 a0v = *(const bf16x8*)&As[(q * 64 + wm * 32 + cl) * 8];
        bf16x8 a1v = *(const bf16x8*)&As[(q * 64 + wm * 32 + 16 + cl) * 8];
        bf16x8 b0v = *(const bf16x8*)&Bs[(q * 64 + wn * 32 + cl) * 8];
        bf16x8 b1v = *(const bf16x8*)&Bs[(q * 64 + wn * 32 + 16 + cl) * 8];
        acc[0][0] = __builtin_amdgcn_mfma_f32_16x16x32_bf16(a0v, b0v, acc[0][0], 0, 0, 0);
        acc[0][1] = __builtin_amdgcn_mfma_f32_16x16x32_bf16(a0v, b1v, acc[0][1], 0, 0, 0);
        acc[1][0] = __builtin_amdgcn_mfma_f32_16x16x32_bf16(a1v, b0v, acc[1][0], 0, 0, 0);
        acc[1][1] = __builtin_amdgcn_mfma_f32_16x16x32_bf16(a1v, b1v, acc[1][1], 0, 0, 0);
        __syncthreads();
    }
    int q = lane >> 4, cl = lane & 15;
    float* Obf = out + (long)blockIdx.z * sO;
    bf16_t* Obh = (bf16_t*)out + (long)blockIdx.z * sO;
    for (int mt = 0; mt < 2; ++mt)
        for (int nt = 0; nt < 2; ++nt)
            #pragma unroll
            for (int r = 0; r < 4; ++r) {
                int row = row0 + wm * 32 + mt * 16 + q * 4 + r;
                if (row >= M) continue;
                int col = col0 + wn * 32 + nt * 16 + cl;
                float v = acc[mt][nt][r];
                if (bias) v += bias[col];
                if (flags & GEMM_GELU) v = 0.5f * v * (1.f + erff(v * 0.70710678118654752f));
                long oidx = (long)row * Nd + col;
                if (flags & GEMM_OUTBF16) Obh[oidx] = (bf16_t)v;
                else if (flags & GEMM_ACC) Obf[oidx] += v;
                else Obf[oidx] = v;
            }
}

// BN5 stats over bf16 y5 [b,d,n]
__global__ __launch_bounds__(256) void bn5_stats_bf16_kernel(const bf16_t* __restrict__ y5,
                                                             const float* __restrict__ g,
                                                             const float* __restrict__ bb,
                                                             float* __restrict__ scale, float* __restrict__ shift) {
    __shared__ double ssum[256], ssq[256];
    int d = blockIdx.x;
    int tid = threadIdx.x;
    double s = 0.0, sq = 0.0;
    for (int b = 0; b < BB; ++b) {
        const bf16_t* row = y5 + ((long)b * DD + d) * NN;
        for (int n = tid; n < NN; n += 256) { float v = (float)row[n]; s += v; sq += (double)v * v; }
    }
    ssum[tid] = s; ssq[tid] = sq;
    __syncthreads();
    for (int st = 128; st > 0; st >>= 1) {
        if (tid < st) { ssum[tid] += ssum[tid + st]; ssq[tid] += ssq[tid + st]; }
        __syncthreads();
    }
    if (tid == 0) {
        double cnt = (double)BB * NN;
        double mean = ssum[0] / cnt;
        double var = ssq[0] / cnt - mean * mean;
        float inv = rsqrtf((float)var + EPSF);
        float sc = g[d] * inv;
        scale[d] = sc;
        shift[d] = bb[d] - (float)mean * sc;
    }
}

// tokens from bf16 y5
__global__ void pool_bf16_kernel(const bf16_t* __restrict__ y5, const float* __restrict__ scale,
                                 const float* __restrict__ shift, const float* __restrict__ cls,
                                 float* __restrict__ t) {
    int gid = blockIdx.x * blockDim.x + threadIdx.x;
    if (gid >= BB * TOK * DD) return;
    int d = gid % DD; int l = (gid / DD) % TOK; int b = gid / (DD * TOK);
    float v;
    if (l == 0) {
        v = cls[d];
    } else {
        int pp = l - 1;
        const bf16_t* row = y5 + ((long)b * DD + d) * NN + pp * PSZ;
        float sc = scale[d], sh = shift[d];
        float m = -INFINITY;
        for (int i = 0; i < PSZ; ++i) {
            float u = (float)row[i] * sc + sh;
            u = (u >= 0.f) ? u : 0.2f * u;
            m = fmaxf(m, u);
        }
        v = m;
    }
    t[gid] = v;
}

// LN: fp32 stats over t (+pos in-place), bf16 normalized output (GEMM A operand)
__global__ __launch_bounds__(256) void ln_kernel(float* __restrict__ t, const float* __restrict__ pos,
                                                 const float* __restrict__ g, const float* __restrict__ bb,
                                                 bf16_t* __restrict__ hn, int addpos) {
    __shared__ double s1[256], s2[256];
    long r = blockIdx.x;
    int tid = threadIdx.x;
    float vals[4];
    double s = 0.0, sq = 0.0;
    for (int i = 0; i < 4; ++i) {
        int d = tid + i * 256;
        float v = t[r * DD + d];
        if (addpos) { v += pos[r * DD + d]; t[r * DD + d] = v; }
        vals[i] = v; s += v; sq += (double)v * v;
    }
    s1[tid] = s; s2[tid] = sq;
    __syncthreads();
    for (int st = 128; st > 0; st >>= 1) {
        if (tid < st) { s1[tid] += s1[tid + st]; s2[tid] += s2[tid + st]; }
        __syncthreads();
    }
    double mean = s1[0] / DD;
    float var = (float)(s2[0] / DD - mean * mean);
    float fm = (float)mean;
    float inv = rsqrtf(var + EPSF);
    for (int i = 0; i < 4; ++i) {
        int d = tid + i * 256;
        hn[r * DD + d] = (bf16_t)((vals[i] - fm) * inv * g[d] + bb[d]);
    }
}

__global__ __launch_bounds__(256) void attn_kernel(const float* __restrict__ qkv, bf16_t* __restrict__ z) {
    __shared__ float ks[TOK][DHH + 1];
    __shared__ float vs[TOK][DHH + 1];
    __shared__ float ss[TOK][TOK];
    int bh = blockIdx.x;
    int b = bh / HH, h = bh % HH;
    int tid = threadIdx.x;
    for (int i = tid; i < TOK * DHH; i += 256) {
        int l = i / DHH, d = i % DHH;
        long base = (long)(b * TOK + l) * 1536;
        ks[l][d] = qkv[base + 512 + h * DHH + d];
        vs[l][d] = qkv[base + 1024 + h * DHH + d];
    }
    __syncthreads();
    for (int i = tid; i < TOK * TOK; i += 256) {
        int l = i / TOK, m = i % TOK;
        const float* qrow = qkv + (long)(b * TOK + l) * 1536 + h * DHH;
        float acc = 0.f;
        for (int d = 0; d < DHH; ++d) acc += qrow[d] * ks[m][d];
        ss[l][m] = acc * 0.125f;
    }
    __syncthreads();
    if (tid < TOK) {
        float mx = -INFINITY;
        for (int m = 0; m < TOK; ++m) mx = fmaxf(mx, ss[tid][m]);
        float sum = 0.f;
        for (int m = 0; m < TOK; ++m) { float e = expf(ss[tid][m] - mx); ss[tid][m] = e; sum += e; }
        float invs = 1.f / sum;
        for (int m = 0; m < TOK; ++m) ss[tid][m] *= invs;
    }
    __syncthreads();
    for (int i = tid; i < TOK * DHH; i += 256) {
        int l = i / DHH, d = i % DHH;
        float acc = 0.f;
        for (int m = 0; m < TOK; ++m) acc += ss[l][m] * vs[m][d];
        z[(long)(b * TOK + l) * INNER_ + h * DHH + d] = (bf16_t)acc;
    }
}

__global__ void final_kernel(const float* __restrict__ t, float* __restrict__ out) {
    int gid = blockIdx.x * blockDim.x + threadIdx.x;
    if (gid >= BB * PP * DD) return;
    int d = gid % DD; int p = (gid / DD) % PP; int b = gid / (DD * PP);
    out[gid] = t[((long)b * TOK + 1 + p) * DD + d];
}

static inline int ceil_div(long a, long b) { return (int)((a + b - 1) / b); }

extern "C" void kernel_launch(void* const* d_in, const int* in_sizes, int n_in,
                              void* d_out, int out_size, void* d_ws, size_t ws_size,
                              hipStream_t stream) {
    const float* x    = (const float*)d_in[0];
    const float* pos  = (const float*)d_in[1];
    const float* w1   = (const float*)d_in[2];
    const float* g1   = (const float*)d_in[3];
    const float* b1   = (const float*)d_in[4];
    const float* w2   = (const float*)d_in[5];
    const float* g2   = (const float*)d_in[6];
    const float* b2   = (const float*)d_in[7];
    const float* w3   = (const float*)d_in[8];
    const float* g3   = (const float*)d_in[9];
    const float* b3   = (const float*)d_in[10];
    const float* w4   = (const float*)d_in[11];
    const float* g4   = (const float*)d_in[12];
    const float* b4   = (const float*)d_in[13];
    const float* w5   = (const float*)d_in[14];
    const float* g5   = (const float*)d_in[15];
    const float* b5   = (const float*)d_in[16];
    const float* cls  = (const float*)d_in[17];
    const float* ln1g = (const float*)d_in[18];
    const float* ln1b = (const float*)d_in[19];
    const float* wqkv = (const float*)d_in[20];
    const float* wout = (const float*)d_in[21];
    const float* bout = (const float*)d_in[22];
    const float* ln2g = (const float*)d_in[23];
    const float* ln2b = (const float*)d_in[24];
    const float* wff1 = (const float*)d_in[25];
    const float* bff1 = (const float*)d_in[26];
    const float* wff2 = (const float*)d_in[27];
    const float* bff2 = (const float*)d_in[28];
    float* out = (float*)d_out;

    // ---- workspace layout ----
    char* ws = (char*)d_ws;
    size_t off = 0;
    auto alloc = [&](size_t bytes) -> char* {
        char* ptr = ws + off;
        off = (off + bytes + 255) & ~(size_t)255;
        return ptr;
    };
    float*  h      = (float*)alloc((size_t)BB * 512 * NN * 4);   // 33.5 MB; reused as y5 BF16 later
    float*  t      = (float*)alloc((size_t)BB * TOK * DD * 4);
    bf16_t* hnb    = (bf16_t*)alloc((size_t)BB * TOK * DD * 4);
    float*  qkvb   = (float*)alloc((size_t)BB * TOK * 1536 * 4);
    bf16_t* zbb    = (bf16_t*)alloc((size_t)BB * TOK * INNER_ * 4);
    bf16_t* ubb    = (bf16_t*)alloc((size_t)BB * TOK * MLPD * 4);
    double* dsum   = (double*)alloc(1024 * 8);
    double* dsq    = (double*)alloc(1024 * 8);
    float*  scaleb = (float*)alloc(1024 * 4);
    float*  shiftb = (float*)alloc(1024 * 4);
    size_t ubase = off;

    // union view 1 (conv phase): pts, xx, idxb, pbuf, qbuf, dist
    size_t uoff = ubase;
    auto ualloc = [&](size_t bytes) -> char* {
        char* ptr = ws + uoff;
        uoff = (uoff + bytes + 255) & ~(size_t)255;
        return ptr;
    };
    float* pts  = (float*)ualloc((size_t)BB * 3 * NN * 4);
    float* xx   = (float*)ualloc((size_t)BB * NN * 4);
    int*   idxb = (int*)  ualloc((size_t)BB * NN * KK * 4);
    float* pbuf = (float*)ualloc((size_t)BB * NN * 256 * 4);
    float* qbuf = (float*)ualloc((size_t)BB * NN * 256 * 4);
    size_t dist_rel = uoff - ubase;
    float* distb = (float*)(ws + uoff);
    // maxb/minb alias the dist buffer (dist is dead after topk); full mode only.
    float* maxb  = distb;
    float* minb  = distb + (size_t)BB * NN * 256;

    // union view 2 (stage 3/4, bf16 path): hT + transposed/converted bf16 weights
    size_t voff = ubase;
    auto valloc = [&](size_t bytes) -> char* {
        char* ptr = ws + voff;
        voff = (voff + bytes + 255) & ~(size_t)255;
        return ptr;
    };
    bf16_t* hT     = (bf16_t*)valloc((size_t)BB * NN * 512 * 2);
    bf16_t* wTqkv  = (bf16_t*)valloc((size_t)DEPTH_ * 1536 * DD * 2);
    bf16_t* wTout  = (bf16_t*)valloc((size_t)DEPTH_ * DD * INNER_ * 2);
    bf16_t* wTff1  = (bf16_t*)valloc((size_t)DEPTH_ * MLPD * DD * 2);
    bf16_t* wTff2  = (bf16_t*)valloc((size_t)DEPTH_ * DD * MLPD * 2);
    bf16_t* w5b    = (bf16_t*)valloc((size_t)DD * 512 * 2);
    size_t stage_bf16 = voff - ubase;

    size_t conv_full  = dist_rel + (size_t)BB * NN * NN * 4;
    size_t conv_batch = dist_rel + (size_t)NN * NN * 4;

    auto mx = [](size_t a, size_t b) { return a > b ? a : b; };
    bool use_bf16 = ws_size >= ubase + mx(conv_batch, stage_bf16);
    bool full     = ws_size >= ubase + mx(conv_full, stage_bf16);
    if (!use_bf16) return;  // insufficient scratch
    bf16_t* y5bf = (bf16_t*)h;                           // 32 MB fits in h's 33.5 MB slot

    // ---- stage 1: transpose points ----
    transpose_x_kernel<<<ceil_div((long)BB * NN * 3, 256), 256, 0, stream>>>(x, pts);

    // ---- stage 2: four EdgeConv blocks ----
    const int NTRI = 136;   // 16*17/2 upper-triangle 128x128 tiles
    auto run_conv = [&](const float* xin, int xbs, int C, const float* w,
                        const float* g, const float* bb, float* hout, int O) {
        sqnorm_kernel<<<ceil_div((long)BB * NN, 256), 256, 0, stream>>>(xin, xbs, C, xx);
        if (full) {
            dist_kernel<<<dim3(NTRI, 1, BB), 256, 0, stream>>>(xin, xbs, C, xx, 0, distb);
            topk_kernel<<<dim3(NN / 4, BB), 256, 0, stream>>>(distb, 0, idxb);
        } else {
            for (int b = 0; b < BB; ++b) {
                dist_kernel<<<dim3(NTRI, 1, 1), 256, 0, stream>>>(xin, xbs, C, xx, b, distb);
                topk_kernel<<<dim3(NN / 4, 1), 256, 0, stream>>>(distb, b, idxb);
            }
        }
        {
            dim3 grid(NN / 32, O / 32, BB);
            pq_kernel<<<grid, 256, 0, stream>>>(xin, xbs, C, w, O, pbuf, qbuf);
        }
        zero_stats_kernel<<<4, 256, 0, stream>>>(dsum, dsq);
        if (full) {
            edge_gather_kernel<<<2048, 256, 0, stream>>>(pbuf, qbuf, idxb, O, dsum, dsq, maxb, minb);
            bn_finalize_kernel<<<1, 256, 0, stream>>>(dsum, dsq, g, bb, O, (double)BB * NN * KK, scaleb, shiftb);
            edge_finalize_kernel<<<dim3(NN / 32, O / 32, BB), 256, 0, stream>>>(
                maxb, minb, O, scaleb, shiftb, hout, 512 * NN);
        } else {
            edge_stats_kernel<<<256, 256, 0, stream>>>(pbuf, qbuf, idxb, O, dsum, dsq);
            bn_finalize_kernel<<<1, 256, 0, stream>>>(dsum, dsq, g, bb, O, (double)BB * NN * KK, scaleb, shiftb);
            edge_out_kernel<<<ceil_div((long)BB * NN * O, 256), 256, 0, stream>>>(
                pbuf, qbuf, idxb, O, scaleb, shiftb, hout, 512 * NN);
        }
    };
    run_conv(pts, 3 * NN, 3, w1, g1, b1, h, 64);
    run_conv(h, 512 * NN, 64, w2, g2, b2, h + 64 * NN, 64);
    run_conv(h + 64 * NN, 512 * NN, 64, w3, g3, b3, h + 128 * NN, 128);
    run_conv(h + 128 * NN, 512 * NN, 128, w4, g4, b4, h + 256 * NN, 256);

    const int M = BB * TOK;  // 520 rows

    // ---- transposes/converts: h -> hT (bf16), weights -> [N][K] bf16, w5 -> bf16 ----
    transpose_cvt_kernel<<<dim3(NN / 32, 512 / 32, BB), 256, 0, stream>>>(
        h, hT, 512, NN, (long)512 * NN, (long)NN * 512);
    transpose_cvt_kernel<<<dim3(1536 / 32, DD / 32, DEPTH_), 256, 0, stream>>>(
        wqkv, wTqkv, DD, 1536, (long)DD * 1536, (long)1536 * DD);
    transpose_cvt_kernel<<<dim3(DD / 32, INNER_ / 32, DEPTH_), 256, 0, stream>>>(
        wout, wTout, INNER_, DD, (long)INNER_ * DD, (long)DD * INNER_);
    transpose_cvt_kernel<<<dim3(MLPD / 32, DD / 32, DEPTH_), 256, 0, stream>>>(
        wff1, wTff1, DD, MLPD, (long)DD * MLPD, (long)MLPD * DD);
    transpose_cvt_kernel<<<dim3(DD / 32, MLPD / 32, DEPTH_), 256, 0, stream>>>(
        wff2, wTff2, MLPD, DD, (long)MLPD * DD, (long)DD * MLPD);
    cvt_bf16_kernel<<<ceil_div((long)DD * 512 / 8, 256), 256, 0, stream>>>(w5, w5b, (long)DD * 512 / 8);

    // ---- stage 3: conv5 (MFMA, bf16 out into h's slot) + BN + pool ----
    gemm_bf16_kernel<<<dim3(NN / 64, DD / 64, BB), 256, 0, stream>>>(
        w5b, hT, nullptr, (float*)y5bf, DD, 512, NN, 0L, (long)NN * 512, (long)DD * NN, GEMM_OUTBF16);
    bn5_stats_bf16_kernel<<<DD, 256, 0, stream>>>(y5bf, g5, b5, scaleb, shiftb);
    pool_bf16_kernel<<<ceil_div((long)BB * TOK * DD, 256), 256, 0, stream>>>(y5bf, scaleb, shiftb, cls, t);

    // ---- stage 4: transformer (MFMA GEMMs, bf16 A operands everywhere) ----
    for (int i = 0; i < DEPTH_; ++i) {
        ln_kernel<<<M, 256, 0, stream>>>(t, pos, ln1g + i * DD, ln1b + i * DD, hnb, 1);
        gemm_bf16_kernel<<<dim3(1536 / 64, ceil_div(M, 64), 1), 256, 0, stream>>>(
            hnb, wTqkv + (size_t)i * 1536 * DD, nullptr, qkvb, M, DD, 1536, 0L, 0L, 0L, 0);
        attn_kernel<<<BB * HH, 256, 0, stream>>>(qkvb, zbb);
        gemm_bf16_kernel<<<dim3(DD / 64, ceil_div(M, 64), 1), 256, 0, stream>>>(
            zbb, wTout + (size_t)i * DD * INNER_, bout + i * DD, t, M, INNER_, DD, 0L, 0L, 0L, GEMM_ACC);
        ln_kernel<<<M, 256, 0, stream>>>(t, nullptr, ln2g + i * DD, ln2b + i * DD, hnb, 0);
        gemm_bf16_kernel<<<dim3(MLPD / 64, ceil_div(M, 64), 1), 256, 0, stream>>>(
            hnb, wTff1 + (size_t)i * MLPD * DD, bff1 + i * MLPD, (float*)ubb, M, DD, MLPD,
            0L, 0L, 0L, GEMM_GELU | GEMM_OUTBF16);
        gemm_bf16_kernel<<<dim3(DD / 64, ceil_div(M, 64), 1), 256, 0, stream>>>(
            ubb, wTff2 + (size_t)i * DD * MLPD, bff2 + i * DD, t, M, MLPD, DD, 0L, 0L, 0L, GEMM_ACC);
    }

    // ---- stage 5: output t[:,1:] ----
    final_kernel<<<ceil_div((long)BB * PP * DD, 256), 256, 0, stream>>>(t, out);
}